// Round 3
// baseline (6303.093 us; speedup 1.0000x reference)
//
#include <hip/hip_runtime.h>
#include <hip/hip_bf16.h>
#include <math.h>

#define L_SEQ 2048
#define DIM_ 1024
#define DINNER 2048
#define DTRANK 64
#define DSTATE 16
#define NEXP 8
#define HIDDEN 4096

static __device__ __forceinline__ float sigmoidf_(float x){ return 1.f/(1.f+expf(-x)); }
static __device__ __forceinline__ float softplusf_(float x){ return fmaxf(x,0.f) + log1pf(expf(-fabsf(x))); }
static __device__ __forceinline__ float geluf_(float x){ return 0.5f*x*(1.f+erff(x*0.70710678118654752f)); }

// ---------------- RMSNorm: o = x * sqrt(DIM) / max(||x||, 1e-12) ----------------
__global__ __launch_bounds__(256) void rmsnorm_k(const float* __restrict__ x, float* __restrict__ o){
  const int l = blockIdx.x;
  const float4 v = *(const float4*)&x[(size_t)l*DIM_ + threadIdx.x*4];
  float s = v.x*v.x + v.y*v.y + v.z*v.z + v.w*v.w;
  #pragma unroll
  for (int off=1; off<64; off<<=1) s += __shfl_xor(s, off);
  __shared__ float red[4];
  if ((threadIdx.x & 63)==0) red[threadIdx.x>>6] = s;
  __syncthreads();
  float tot = red[0]+red[1]+red[2]+red[3];
  float scale = 32.f / fmaxf(sqrtf(tot), 1e-12f);
  float4 r; r.x=v.x*scale; r.y=v.y*scale; r.z=v.z*scale; r.w=v.w*scale;
  *(float4*)&o[(size_t)l*DIM_ + threadIdx.x*4] = r;
}

// ---------------- fp32 tiled GEMM, C[M,N] = A[M,K] @ W[N,K]^T ----------------
// EPI: 0 none, 1 softplus(v+bias[n]), 2 gelu(v), 3 v+addm[m,n]
#define TM 128
#define TN 64
#define TKK 16

template<int EPI>
__global__ __launch_bounds__(256) void gemm_nt(
    const float* __restrict__ A, int lda,
    const float* __restrict__ W, int ldw,
    float* __restrict__ C, int ldc,
    int M, int N, int K,
    const float* __restrict__ bias,
    const float* __restrict__ addm, int ldadd)
{
  __shared__ float As[TKK][TM+4];
  __shared__ float Bs[TKK][TN+4];
  const int bm = blockIdx.x * TM;
  const int bn = blockIdx.y * TN;
  const int tid = threadIdx.x;
  const int ty = tid >> 4;        // 0..15 -> 8 rows each
  const int tx = tid & 15;        // 0..15 -> 4 cols each
  const int ar = tid >> 2;        // 0..63
  const int ak = (tid & 3) * 4;   // 0,4,8,12
  float acc[8][4];
  #pragma unroll
  for (int i=0;i<8;i++){ acc[i][0]=0.f;acc[i][1]=0.f;acc[i][2]=0.f;acc[i][3]=0.f; }

  for (int k0 = 0; k0 < K; k0 += TKK) {
    #pragma unroll
    for (int h2=0; h2<2; ++h2) {
      const int m = bm + ar + h2*64;
      float4 v = make_float4(0.f,0.f,0.f,0.f);
      if (m < M) v = *(const float4*)&A[(size_t)m*lda + k0 + ak];
      As[ak+0][ar+h2*64]=v.x; As[ak+1][ar+h2*64]=v.y; As[ak+2][ar+h2*64]=v.z; As[ak+3][ar+h2*64]=v.w;
    }
    {
      const int n = bn + ar;
      float4 v = make_float4(0.f,0.f,0.f,0.f);
      if (n < N) v = *(const float4*)&W[(size_t)n*ldw + k0 + ak];
      Bs[ak+0][ar]=v.x; Bs[ak+1][ar]=v.y; Bs[ak+2][ar]=v.z; Bs[ak+3][ar]=v.w;
    }
    __syncthreads();
    #pragma unroll
    for (int k=0;k<TKK;k++){
      const float4 b  = *(const float4*)&Bs[k][tx*4];
      const float4 a0 = *(const float4*)&As[k][ty*8];
      const float4 a1 = *(const float4*)&As[k][ty*8+4];
      const float av[8] = {a0.x,a0.y,a0.z,a0.w,a1.x,a1.y,a1.z,a1.w};
      const float bv[4] = {b.x,b.y,b.z,b.w};
      #pragma unroll
      for (int i=0;i<8;i++)
        #pragma unroll
        for (int j=0;j<4;j++)
          acc[i][j] = fmaf(av[i], bv[j], acc[i][j]);
    }
    __syncthreads();
  }

  #pragma unroll
  for (int i=0;i<8;i++){
    const int m = bm + ty*8 + i;
    if (m >= M) continue;
    const int n0 = bn + tx*4;
    float out[4];
    #pragma unroll
    for (int j=0;j<4;j++){
      float v = acc[i][j];
      const int n = n0 + j;
      if (EPI==1) v = softplusf_(v + bias[n < N ? n : 0]);
      else if (EPI==2) v = geluf_(v);
      else if (EPI==3) v = v + ((n < N) ? addm[(size_t)m*ldadd + n] : 0.f);
      out[j]=v;
    }
    if (n0 + 3 < N) {
      *(float4*)&C[(size_t)m*ldc+n0] = make_float4(out[0],out[1],out[2],out[3]);
    } else {
      for (int j=0;j<4;j++) if (n0+j < N) C[(size_t)m*ldc+n0+j]=out[j];
    }
  }
}

// ---------------- grouped GEMM over experts (MoE) ----------------
template<int EPI, bool GATHER>
__global__ __launch_bounds__(256) void gemm_nt_group(
    const float* __restrict__ A, int lda,
    const float* __restrict__ Wall, int ldw, size_t wstride,
    float* __restrict__ C, int ldc,
    const int* __restrict__ offs,   // E+1 exclusive offsets
    const int* __restrict__ perm,   // assignment -> token row (GATHER only)
    int N, int K)
{
  const int e = blockIdx.z;
  const int base = offs[e];
  const int Me = offs[e+1] - base;
  const int bm = blockIdx.x * TM;
  if (bm >= Me) return;
  const float* __restrict__ W = Wall + (size_t)e * wstride;

  __shared__ float As[TKK][TM+4];
  __shared__ float Bs[TKK][TN+4];
  const int bn = blockIdx.y * TN;
  const int tid = threadIdx.x;
  const int ty = tid >> 4;
  const int tx = tid & 15;
  const int ar = tid >> 2;
  const int ak = (tid & 3) * 4;
  float acc[8][4];
  #pragma unroll
  for (int i=0;i<8;i++){ acc[i][0]=0.f;acc[i][1]=0.f;acc[i][2]=0.f;acc[i][3]=0.f; }

  for (int k0 = 0; k0 < K; k0 += TKK) {
    #pragma unroll
    for (int h2=0; h2<2; ++h2) {
      const int lm = bm + ar + h2*64;
      float4 v = make_float4(0.f,0.f,0.f,0.f);
      if (lm < Me) {
        const int row = GATHER ? perm[base+lm] : (base+lm);
        v = *(const float4*)&A[(size_t)row*lda + k0 + ak];
      }
      As[ak+0][ar+h2*64]=v.x; As[ak+1][ar+h2*64]=v.y; As[ak+2][ar+h2*64]=v.z; As[ak+3][ar+h2*64]=v.w;
    }
    {
      const int n = bn + ar;
      float4 v = make_float4(0.f,0.f,0.f,0.f);
      if (n < N) v = *(const float4*)&W[(size_t)n*ldw + k0 + ak];
      Bs[ak+0][ar]=v.x; Bs[ak+1][ar]=v.y; Bs[ak+2][ar]=v.z; Bs[ak+3][ar]=v.w;
    }
    __syncthreads();
    #pragma unroll
    for (int k=0;k<TKK;k++){
      const float4 b  = *(const float4*)&Bs[k][tx*4];
      const float4 a0 = *(const float4*)&As[k][ty*8];
      const float4 a1 = *(const float4*)&As[k][ty*8+4];
      const float av[8] = {a0.x,a0.y,a0.z,a0.w,a1.x,a1.y,a1.z,a1.w};
      const float bv[4] = {b.x,b.y,b.z,b.w};
      #pragma unroll
      for (int i=0;i<8;i++)
        #pragma unroll
        for (int j=0;j<4;j++)
          acc[i][j] = fmaf(av[i], bv[j], acc[i][j]);
    }
    __syncthreads();
  }

  #pragma unroll
  for (int i=0;i<8;i++){
    const int lm = bm + ty*8 + i;
    if (lm >= Me) continue;
    const int n0 = bn + tx*4;
    float out[4];
    #pragma unroll
    for (int j=0;j<4;j++){
      float v = acc[i][j];
      if (EPI==2) v = geluf_(v);
      out[j]=v;
    }
    if (n0 + 3 < N) {
      *(float4*)&C[(size_t)(base+lm)*ldc+n0] = make_float4(out[0],out[1],out[2],out[3]);
    } else {
      for (int j=0;j<4;j++) if (n0+j < N) C[(size_t)(base+lm)*ldc+n0+j]=out[j];
    }
  }
}

// ---------------- causal depthwise conv (width 4) + SiLU ----------------
__global__ __launch_bounds__(256) void conv_silu_k(
    const float* __restrict__ xr, const float* __restrict__ cw,
    const float* __restrict__ cb, float* __restrict__ xc)
{
  const int l = blockIdx.x;
  const int d = blockIdx.y*256 + threadIdx.x;
  const float4 w = *(const float4*)&cw[d*4];
  const float wv[4] = {w.x,w.y,w.z,w.w};
  float s = cb[d];
  #pragma unroll
  for (int j=0;j<4;j++){
    const int ll = l - 3 + j;
    if (ll >= 0) s = fmaf(wv[j], xr[(size_t)ll*(2*DINNER) + d], s);
  }
  xc[(size_t)l*DINNER + d] = s * sigmoidf_(s);
}

// ---------------- selective scan (fused epilogue: (+u*D) * silu(res)) ----------------
// block = 16 channels x 16 states; 128 blocks cover d_inner=2048
__global__ __launch_bounds__(256) void scan_k(
    const float* __restrict__ delta,  // (L, DINNER)
    const float* __restrict__ u,      // xc (L, DINNER)
    const float* __restrict__ xdbl,   // (L, 96); B at +64, C at +80
    const float* __restrict__ res,    // xr + DINNER, ld 2*DINNER
    const float* __restrict__ A_log,  // (DINNER, 16)
    const float* __restrict__ Dp,     // (DINNER)
    float* __restrict__ yout)         // (L, DINNER)
{
  const int d0 = blockIdx.x * 16;
  const int tid = threadIdx.x;
  const int dl = tid >> 4;   // channel within block
  const int nn = tid & 15;   // state
  const int d = d0 + dl;
  const float Adn = -expf(A_log[(size_t)d*DSTATE + nn]);
  float h = 0.f;
  __shared__ float sdel[64][16];
  __shared__ float su[64][16];
  __shared__ float sB[64][16];
  __shared__ float sC[64][16];
  __shared__ float sres[64][16];
  __shared__ float sy[64][16];
  __shared__ float sD[16];
  if (tid < 16) sD[tid] = Dp[d0 + tid];

  for (int l0 = 0; l0 < L_SEQ; l0 += 64) {
    #pragma unroll
    for (int i=0;i<4;i++){
      const int idx = tid + 256*i;
      const int r = idx >> 4, c = idx & 15;
      const int l = l0 + r;
      sdel[r][c] = delta[(size_t)l*DINNER + d0 + c];
      su[r][c]   = u[(size_t)l*DINNER + d0 + c];
      sres[r][c] = res[(size_t)l*(2*DINNER) + d0 + c];
      sB[r][c]   = xdbl[(size_t)l*96 + DTRANK + c];
      sC[r][c]   = xdbl[(size_t)l*96 + DTRANK + DSTATE + c];
    }
    __syncthreads();
    #pragma unroll 4
    for (int j=0;j<64;j++){
      const float dlt = sdel[j][dl];
      const float uu  = su[j][dl];
      const float dA  = expf(dlt * Adn);
      h = fmaf(dA, h, dlt * sB[j][nn] * uu);
      float p = h * sC[j][nn];
      p += __shfl_xor(p, 1);
      p += __shfl_xor(p, 2);
      p += __shfl_xor(p, 4);
      p += __shfl_xor(p, 8);
      if (nn == 0) sy[j][dl] = p;
    }
    __syncthreads();
    #pragma unroll
    for (int i=0;i<4;i++){
      const int idx = tid + 256*i;
      const int r = idx >> 4, c = idx & 15;
      const int l = l0 + r;
      const float rv = sres[r][c];
      const float yv = (sy[r][c] + su[r][c]*sD[c]) * (rv * sigmoidf_(rv));
      yout[(size_t)l*DINNER + d0 + c] = yv;
    }
    __syncthreads();
  }
}

// ---------------- gate: dot(8 experts) + softmax + top2 + renorm + count ----------------
__global__ __launch_bounds__(256) void gate_topk_k(
    const float* __restrict__ xn, const float* __restrict__ gw,
    int* __restrict__ tidx, float* __restrict__ tw, int* __restrict__ cnt)
{
  const int l = blockIdx.x;
  const int t = threadIdx.x;
  const float4 xv = *(const float4*)&xn[(size_t)l*DIM_ + t*4];
  float acc[NEXP];
  #pragma unroll
  for (int e=0;e<NEXP;e++){
    const float4 g = *(const float4*)&gw[(size_t)e*DIM_ + t*4];
    acc[e] = xv.x*g.x + xv.y*g.y + xv.z*g.z + xv.w*g.w;
  }
  #pragma unroll
  for (int e=0;e<NEXP;e++)
    #pragma unroll
    for (int off=1; off<64; off<<=1) acc[e] += __shfl_xor(acc[e], off);
  __shared__ float red[4][NEXP];
  if ((t & 63)==0){
    #pragma unroll
    for (int e=0;e<NEXP;e++) red[t>>6][e] = acc[e];
  }
  __syncthreads();
  if (t==0){
    float g[NEXP];
    float m = -1e30f;
    #pragma unroll
    for (int e=0;e<NEXP;e++){ g[e]=red[0][e]+red[1][e]+red[2][e]+red[3][e]; m=fmaxf(m,g[e]); }
    float p[NEXP];
    #pragma unroll
    for (int e=0;e<NEXP;e++) p[e] = expf(g[e]-m);
    int i0=0;
    #pragma unroll
    for (int e=1;e<NEXP;e++) if (p[e] > p[i0]) i0=e;
    int i1 = (i0==0)?1:0;
    #pragma unroll
    for (int e=0;e<NEXP;e++) if (e!=i0 && p[e] > p[i1]) i1=e;
    const float w0=p[i0], w1=p[i1], inv=1.f/(w0+w1);
    tidx[2*l]=i0; tidx[2*l+1]=i1;
    tw[2*l]=w0*inv; tw[2*l+1]=w1*inv;
    atomicAdd(&cnt[i0],1); atomicAdd(&cnt[i1],1);
  }
}

__global__ void offsets_k(const int* __restrict__ cnt, int* __restrict__ off){
  if (threadIdx.x==0){
    int a=0;
    for (int e=0;e<NEXP;e++){ off[e]=a; a+=cnt[e]; }
    off[NEXP]=a;
  }
}

__global__ __launch_bounds__(256) void scatter_k(
    const int* __restrict__ tidx, const int* __restrict__ off,
    int* __restrict__ cur, int* __restrict__ perm, int* __restrict__ slot)
{
  const int t = blockIdx.x*256 + threadIdx.x;
  if (t >= L_SEQ) return;
  #pragma unroll
  for (int k=0;k<2;k++){
    const int e = tidx[2*t+k];
    const int pos = off[e] + atomicAdd(&cur[e],1);
    perm[pos] = t;
    slot[2*t+k] = pos;
  }
}

// ---------------- final: out = skip + w0*y2[slot0] + w1*y2[slot1] ----------------
__global__ __launch_bounds__(256) void final_k(
    const float* __restrict__ x, const float* __restrict__ y2,
    const int* __restrict__ slot, const float* __restrict__ tw,
    float* __restrict__ out)
{
  const int l = blockIdx.x;
  const int c = threadIdx.x*4;
  const float4 xv = *(const float4*)&x[(size_t)l*DIM_ + c];
  const int s0 = slot[2*l], s1 = slot[2*l+1];
  const float w0 = tw[2*l], w1 = tw[2*l+1];
  const float4 a = *(const float4*)&y2[(size_t)s0*DIM_ + c];
  const float4 b = *(const float4*)&y2[(size_t)s1*DIM_ + c];
  float4 r;
  r.x = xv.x + w0*a.x + w1*b.x;
  r.y = xv.y + w0*a.y + w1*b.y;
  r.z = xv.z + w0*a.z + w1*b.z;
  r.w = xv.w + w0*a.w + w1*b.w;
  *(float4*)&out[(size_t)l*DIM_ + c] = r;
}

extern "C" void kernel_launch(void* const* d_in, const int* in_sizes, int n_in,
                              void* d_out, int out_size, void* d_ws, size_t ws_size,
                              hipStream_t stream) {
  const float* x         = (const float*)d_in[0];
  const float* in_proj_w = (const float*)d_in[1];
  const float* conv_w    = (const float*)d_in[2];
  const float* conv_b    = (const float*)d_in[3];
  const float* x_proj_w  = (const float*)d_in[4];
  const float* dt_proj_w = (const float*)d_in[5];
  const float* dt_proj_b = (const float*)d_in[6];
  const float* A_log     = (const float*)d_in[7];
  const float* Dp        = (const float*)d_in[8];
  const float* out_proj_w= (const float*)d_in[9];
  const float* gate_w    = (const float*)d_in[10];
  const float* w1        = (const float*)d_in[11];
  const float* w2        = (const float*)d_in[12];
  float* out = (float*)d_out;

  float* f = (float*)d_ws;
  float* xn    = f;                      f += (size_t)L_SEQ*DIM_;       // 2M fl
  float* xr    = f;                      f += (size_t)L_SEQ*2*DINNER;   // 8M fl
  float* xc    = f;                      f += (size_t)L_SEQ*DINNER;     // 4M fl
  float* xdbl  = f;                      f += (size_t)L_SEQ*96;         // .2M fl
  float* delta = f;                      f += (size_t)L_SEQ*DINNER;     // 4M fl
  float* yg    = f;                      f += (size_t)L_SEQ*DINNER;     // 4M fl
  float* xm2   = f;                      f += (size_t)L_SEQ*DIM_;       // 2M fl
  float* y2    = f;                      f += (size_t)2*L_SEQ*DIM_;     // 4M fl
  float* tw    = f;                      f += 2*L_SEQ;
  int* tidx = (int*)f;
  int* cnt  = tidx + 2*L_SEQ;
  int* cur  = cnt + 16;
  int* offs = cur + 16;
  int* perm = offs + 16;
  int* slot = perm + 2*L_SEQ;
  // Aliases (dead-buffer reuse, keeps peak ws ~119 MB):
  //  - xm2n reuses xn (xn dead after out_proj epilogue consumes it)
  //  - MoE hidden buffer (2L x HIDDEN = 16.78M fl) reuses xr..yg (20.2M fl),
  //    all dead by the time the MoE GEMMs run.
  float* xm2n = xn;
  float* hbuf = xr;

  // 1. xn = rmsnorm(x)
  rmsnorm_k<<<L_SEQ, 256, 0, stream>>>(x, xn);
  // 2. xr = xn @ in_proj_w^T   (2048 x 4096, K=1024)
  gemm_nt<0><<<dim3(L_SEQ/TM, 2*DINNER/TN), 256, 0, stream>>>(
      xn, DIM_, in_proj_w, DIM_, xr, 2*DINNER, L_SEQ, 2*DINNER, DIM_, nullptr, nullptr, 0);
  // 3. xc = silu(causal depthwise conv(xm) + b)
  conv_silu_k<<<dim3(L_SEQ, DINNER/256), 256, 0, stream>>>(xr, conv_w, conv_b, xc);
  // 4. xdbl = xc @ x_proj_w^T  (2048 x 96, K=2048)
  gemm_nt<0><<<dim3(L_SEQ/TM, (96+TN-1)/TN), 256, 0, stream>>>(
      xc, DINNER, x_proj_w, DINNER, xdbl, 96, L_SEQ, 96, DINNER, nullptr, nullptr, 0);
  // 5. delta = softplus(dt @ dt_proj_w^T + b)  (2048 x 2048, K=64)
  gemm_nt<1><<<dim3(L_SEQ/TM, DINNER/TN), 256, 0, stream>>>(
      xdbl, 96, dt_proj_w, DTRANK, delta, DINNER, L_SEQ, DINNER, DTRANK, dt_proj_b, nullptr, 0);
  // 6. selective scan fused with (+u*D)*silu(res)
  scan_k<<<DINNER/16, 256, 0, stream>>>(delta, xc, xdbl, xr + DINNER, A_log, Dp, yg);
  // 7. xm2 = yg @ out_proj_w^T + xn  (2048 x 1024, K=2048)
  gemm_nt<3><<<dim3(L_SEQ/TM, DIM_/TN), 256, 0, stream>>>(
      yg, DINNER, out_proj_w, DINNER, xm2, DIM_, L_SEQ, DIM_, DINNER, nullptr, xn, DIM_);
  // 8. xm2n = rmsnorm(xm2)   (xm2n aliases xn — xn is dead now)
  rmsnorm_k<<<L_SEQ, 256, 0, stream>>>(xm2, xm2n);
  // 9. routing
  hipMemsetAsync(cnt, 0, 32*sizeof(int), stream);   // cnt + cur
  gate_topk_k<<<L_SEQ, 256, 0, stream>>>(xm2n, gate_w, tidx, tw, cnt);
  offsets_k<<<1, 64, 0, stream>>>(cnt, offs);
  scatter_k<<<L_SEQ/256, 256, 0, stream>>>(tidx, offs, cur, perm, slot);
  // 10. MoE expert GEMMs (sparse == dense reference: zero-weight experts contribute exactly 0)
  gemm_nt_group<2, true><<<dim3(2*L_SEQ/TM, HIDDEN/TN, NEXP), 256, 0, stream>>>(
      xm2n, DIM_, w1, DIM_, (size_t)HIDDEN*DIM_, hbuf, HIDDEN, offs, perm, HIDDEN, DIM_);
  gemm_nt_group<0, false><<<dim3(2*L_SEQ/TM, DIM_/TN, NEXP), 256, 0, stream>>>(
      hbuf, HIDDEN, w2, HIDDEN, (size_t)DIM_*HIDDEN, y2, DIM_, offs, nullptr, DIM_, HIDDEN);
  // 11. combine
  final_k<<<L_SEQ, 256, 0, stream>>>(x, y2, slot, tw, out);
}

// Round 4
// 1893.963 us; speedup vs baseline: 3.3280x; 3.3280x over previous
//
#include <hip/hip_runtime.h>
#include <hip/hip_bf16.h>
#include <math.h>

#define L_SEQ 2048
#define DIM_ 1024
#define DINNER 2048
#define DTRANK 64
#define DSTATE 16
#define NEXP 8
#define HIDDEN 4096
#define PADM 5120   // 4096 expert assignments + per-expert pad to 128

typedef unsigned short ushort_t;
typedef __attribute__((ext_vector_type(8))) short short8;   // 8 bf16 (4 VGPR)
typedef __attribute__((ext_vector_type(4))) float f32x4;    // MFMA acc

static __device__ __forceinline__ float sigmoidf_(float x){ return 1.f/(1.f+expf(-x)); }
static __device__ __forceinline__ float softplusf_(float x){ return fmaxf(x,0.f) + log1pf(expf(-fabsf(x))); }
static __device__ __forceinline__ float geluf_(float x){ return 0.5f*x*(1.f+erff(x*0.70710678118654752f)); }
static __device__ __forceinline__ ushort_t f2bf(float x){   // RNE f32->bf16
  unsigned u = __float_as_uint(x);
  return (ushort_t)((u + 0x7FFFu + ((u>>16)&1u)) >> 16);
}

// ---------------- f32 -> bf16 bulk convert ----------------
__global__ __launch_bounds__(256) void cvt_bf16_k(const float* __restrict__ s,
                                                  ushort_t* __restrict__ d, int n4){
  for (int i = blockIdx.x*256 + threadIdx.x; i < n4; i += gridDim.x*256){
    const float4 v = ((const float4*)s)[i];
    ushort4 o; o.x=f2bf(v.x); o.y=f2bf(v.y); o.z=f2bf(v.z); o.w=f2bf(v.w);
    ((ushort4*)d)[i] = o;
  }
}

// ---------------- RMSNorm ----------------
__global__ __launch_bounds__(256) void rmsnorm_k(const float* __restrict__ x, float* __restrict__ o){
  const int l = blockIdx.x;
  const float4 v = *(const float4*)&x[(size_t)l*DIM_ + threadIdx.x*4];
  float s = v.x*v.x + v.y*v.y + v.z*v.z + v.w*v.w;
  #pragma unroll
  for (int off=1; off<64; off<<=1) s += __shfl_xor(s, off);
  __shared__ float red[4];
  if ((threadIdx.x & 63)==0) red[threadIdx.x>>6] = s;
  __syncthreads();
  float tot = red[0]+red[1]+red[2]+red[3];
  float scale = 32.f / fmaxf(sqrtf(tot), 1e-12f);
  float4 r; r.x=v.x*scale; r.y=v.y*scale; r.z=v.z*scale; r.w=v.w*scale;
  *(float4*)&o[(size_t)l*DIM_ + threadIdx.x*4] = r;
}

// ---------------- fp32 tiled GEMM (kept for mamba path; gate-decision safety) ----------------
#define TM 128
#define TN 64
#define TKK 16

template<int EPI>  // 0 none, 1 softplus(v+bias[n]), 3 v+addm[m,n]
__global__ __launch_bounds__(256) void gemm_nt(
    const float* __restrict__ A, int lda,
    const float* __restrict__ W, int ldw,
    float* __restrict__ C, int ldc,
    int M, int N, int K,
    const float* __restrict__ bias,
    const float* __restrict__ addm, int ldadd)
{
  __shared__ float As[TKK][TM+4];
  __shared__ float Bs[TKK][TN+4];
  const int bm = blockIdx.x * TM;
  const int bn = blockIdx.y * TN;
  const int tid = threadIdx.x;
  const int ty = tid >> 4;
  const int tx = tid & 15;
  const int ar = tid >> 2;
  const int ak = (tid & 3) * 4;
  float acc[8][4];
  #pragma unroll
  for (int i=0;i<8;i++){ acc[i][0]=0.f;acc[i][1]=0.f;acc[i][2]=0.f;acc[i][3]=0.f; }

  for (int k0 = 0; k0 < K; k0 += TKK) {
    #pragma unroll
    for (int h2=0; h2<2; ++h2) {
      const int m = bm + ar + h2*64;
      float4 v = make_float4(0.f,0.f,0.f,0.f);
      if (m < M) v = *(const float4*)&A[(size_t)m*lda + k0 + ak];
      As[ak+0][ar+h2*64]=v.x; As[ak+1][ar+h2*64]=v.y; As[ak+2][ar+h2*64]=v.z; As[ak+3][ar+h2*64]=v.w;
    }
    {
      const int n = bn + ar;
      float4 v = make_float4(0.f,0.f,0.f,0.f);
      if (n < N) v = *(const float4*)&W[(size_t)n*ldw + k0 + ak];
      Bs[ak+0][ar]=v.x; Bs[ak+1][ar]=v.y; Bs[ak+2][ar]=v.z; Bs[ak+3][ar]=v.w;
    }
    __syncthreads();
    #pragma unroll
    for (int k=0;k<TKK;k++){
      const float4 b  = *(const float4*)&Bs[k][tx*4];
      const float4 a0 = *(const float4*)&As[k][ty*8];
      const float4 a1 = *(const float4*)&As[k][ty*8+4];
      const float av[8] = {a0.x,a0.y,a0.z,a0.w,a1.x,a1.y,a1.z,a1.w};
      const float bv[4] = {b.x,b.y,b.z,b.w};
      #pragma unroll
      for (int i=0;i<8;i++)
        #pragma unroll
        for (int j=0;j<4;j++)
          acc[i][j] = fmaf(av[i], bv[j], acc[i][j]);
    }
    __syncthreads();
  }

  #pragma unroll
  for (int i=0;i<8;i++){
    const int m = bm + ty*8 + i;
    if (m >= M) continue;
    const int n0 = bn + tx*4;
    float out[4];
    #pragma unroll
    for (int j=0;j<4;j++){
      float v = acc[i][j];
      const int n = n0 + j;
      if (EPI==1) v = softplusf_(v + bias[n < N ? n : 0]);
      else if (EPI==3) v = v + ((n < N) ? addm[(size_t)m*ldadd + n] : 0.f);
      out[j]=v;
    }
    if (n0 + 3 < N) {
      *(float4*)&C[(size_t)m*ldc+n0] = make_float4(out[0],out[1],out[2],out[3]);
    } else {
      for (int j=0;j<4;j++) if (n0+j < N) C[(size_t)m*ldc+n0+j]=out[j];
    }
  }
}

// ---------------- bf16 MFMA GEMM: C[M,N] = A[M,K] @ W[N,K]^T ----------------
// 128x128 tile, BK=64, 4 waves (2x2), mfma_f32_16x16x32_bf16.
// LDS tiles [128 rows][128B]: 16B chunk c of row r stored at chunk c^(r&7)
// (pre-swizzled GLOBAL source + linear global_load_lds dest + swizzled read — rule 21).
// EPI: 0 plain fp32, 2 gelu->bf16
template<int EPI, bool GROUP>
__global__ __launch_bounds__(256) void gemm_bf16(
    const ushort_t* __restrict__ A,      // [M(or PADM)][K] bf16 row-major
    const ushort_t* __restrict__ Wall,   // [N][K] bf16 (GROUP: per-expert blocks)
    size_t wstride,
    void* __restrict__ Cp, int ldc,
    int K,
    const int* __restrict__ poffs)       // GROUP: [NEXP+1] padded offsets
{
  __shared__ ushort_t Asl[128*64];
  __shared__ ushort_t Bsl[128*64];
  const int bm = blockIdx.x * 128;
  const int bn = blockIdx.y * 128;
  const ushort_t* W = Wall;
  if (GROUP){
    if (bm >= poffs[NEXP]) return;
    int e = 0;
    #pragma unroll
    for (int t=1;t<NEXP;t++) if (bm >= poffs[t]) e = t;
    W = Wall + (size_t)e * wstride;
  }
  const int tid  = threadIdx.x;
  const int lane = tid & 63;
  const int wave = tid >> 6;
  const int wr = wave >> 1, wc = wave & 1;         // 2x2 waves -> 64x64 each

  const f32x4 fzero = {0.f,0.f,0.f,0.f};
  f32x4 acc[4][4];
  #pragma unroll
  for (int m=0;m<4;m++)
    #pragma unroll
    for (int n=0;n<4;n++) acc[m][n] = fzero;

  const int r_lo   = lane & 15;                    // frag row within 16
  const int kgrp   = lane >> 4;                    // 16B chunk within 32-k half
  const int srow   = lane >> 3;                    // staging: row within 8
  const int schunk = (lane&7) ^ ((lane>>3)&7);     // staging: pre-swizzled src chunk

  const int nkt = K >> 6;
  for (int kt = 0; kt < nkt; ++kt){
    // stage A,B 128x64 tiles: 16 x 1KB wave-instructions per tile, 4 per wave
    #pragma unroll
    for (int i=0;i<4;i++){
      const int idx = wave*4 + i;                  // covers LDS rows [idx*8, idx*8+8)
      const int row = idx*8 + srow;
      const ushort_t* ga = A + (size_t)(bm + row)*K + kt*64 + schunk*8;
      const ushort_t* gb = W + (size_t)(bn + row)*K + kt*64 + schunk*8;
      __builtin_amdgcn_global_load_lds(
          (const __attribute__((address_space(1))) void*)ga,
          (__attribute__((address_space(3))) void*)((char*)Asl + idx*1024), 16, 0, 0);
      __builtin_amdgcn_global_load_lds(
          (const __attribute__((address_space(1))) void*)gb,
          (__attribute__((address_space(3))) void*)((char*)Bsl + idx*1024), 16, 0, 0);
    }
    __syncthreads();   // compiler drains vmcnt before barrier
    #pragma unroll
    for (int kk=0;kk<2;kk++){
      const int ch = kk*4 + kgrp;
      short8 a[4], b[4];
      #pragma unroll
      for (int m=0;m<4;m++){
        const int row = wr*64 + m*16 + r_lo;
        a[m] = *(const short8*)((const char*)Asl + row*128 + ((ch ^ (row&7))<<4));
      }
      #pragma unroll
      for (int n=0;n<4;n++){
        const int row = wc*64 + n*16 + r_lo;
        b[n] = *(const short8*)((const char*)Bsl + row*128 + ((ch ^ (row&7))<<4));
      }
      #pragma unroll
      for (int m=0;m<4;m++)
        #pragma unroll
        for (int n=0;n<4;n++)
          acc[m][n] = __builtin_amdgcn_mfma_f32_16x16x32_bf16(a[m], b[n], acc[m][n], 0, 0, 0);
    }
    __syncthreads();
  }

  // epilogue: C/D frag layout col=lane&15, row=(lane>>4)*4+i  [m89-verified]
  const int crow0 = bm + wr*64 + (lane>>4)*4;
  const int ccol0 = bn + wc*64 + (lane&15);
  #pragma unroll
  for (int m=0;m<4;m++){
    #pragma unroll
    for (int n=0;n<4;n++){
      const int col = ccol0 + n*16;
      #pragma unroll
      for (int i=0;i<4;i++){
        const int row = crow0 + m*16 + i;
        const float v = acc[m][n][i];
        if (EPI==2) ((ushort_t*)Cp)[(size_t)row*ldc + col] = f2bf(geluf_(v));
        else        ((float*)Cp)[(size_t)row*ldc + col] = v;
      }
    }
  }
}

// ---------------- causal depthwise conv (width 4) + SiLU ----------------
__global__ __launch_bounds__(256) void conv_silu_k(
    const float* __restrict__ xr, const float* __restrict__ cw,
    const float* __restrict__ cb, float* __restrict__ xc)
{
  const int l = blockIdx.x;
  const int d = blockIdx.y*256 + threadIdx.x;
  const float4 w = *(const float4*)&cw[d*4];
  const float wv[4] = {w.x,w.y,w.z,w.w};
  float s = cb[d];
  #pragma unroll
  for (int j=0;j<4;j++){
    const int ll = l - 3 + j;
    if (ll >= 0) s = fmaf(wv[j], xr[(size_t)ll*(2*DINNER) + d], s);
  }
  xc[(size_t)l*DINNER + d] = s * sigmoidf_(s);
}

// ---------------- selective scan (fused epilogue: (+u*D) * silu(res)) ----------------
__global__ __launch_bounds__(256) void scan_k(
    const float* __restrict__ delta, const float* __restrict__ u,
    const float* __restrict__ xdbl,  const float* __restrict__ res,
    const float* __restrict__ A_log, const float* __restrict__ Dp,
    float* __restrict__ yout)
{
  const int d0 = blockIdx.x * 16;
  const int tid = threadIdx.x;
  const int dl = tid >> 4;
  const int nn = tid & 15;
  const int d = d0 + dl;
  const float Adn = -expf(A_log[(size_t)d*DSTATE + nn]);
  float h = 0.f;
  __shared__ float sdel[64][16];
  __shared__ float su[64][16];
  __shared__ float sB[64][16];
  __shared__ float sC[64][16];
  __shared__ float sres[64][16];
  __shared__ float sy[64][16];
  __shared__ float sD[16];
  if (tid < 16) sD[tid] = Dp[d0 + tid];

  for (int l0 = 0; l0 < L_SEQ; l0 += 64) {
    #pragma unroll
    for (int i=0;i<4;i++){
      const int idx = tid + 256*i;
      const int r = idx >> 4, c = idx & 15;
      const int l = l0 + r;
      sdel[r][c] = delta[(size_t)l*DINNER + d0 + c];
      su[r][c]   = u[(size_t)l*DINNER + d0 + c];
      sres[r][c] = res[(size_t)l*(2*DINNER) + d0 + c];
      sB[r][c]   = xdbl[(size_t)l*96 + DTRANK + c];
      sC[r][c]   = xdbl[(size_t)l*96 + DTRANK + DSTATE + c];
    }
    __syncthreads();
    #pragma unroll 4
    for (int j=0;j<64;j++){
      const float dlt = sdel[j][dl];
      const float uu  = su[j][dl];
      const float dA  = expf(dlt * Adn);
      h = fmaf(dA, h, dlt * sB[j][nn] * uu);
      float p = h * sC[j][nn];
      p += __shfl_xor(p, 1);
      p += __shfl_xor(p, 2);
      p += __shfl_xor(p, 4);
      p += __shfl_xor(p, 8);
      if (nn == 0) sy[j][dl] = p;
    }
    __syncthreads();
    #pragma unroll
    for (int i=0;i<4;i++){
      const int idx = tid + 256*i;
      const int r = idx >> 4, c = idx & 15;
      const int l = l0 + r;
      const float rv = sres[r][c];
      const float yv = (sy[r][c] + su[r][c]*sD[c]) * (rv * sigmoidf_(rv));
      yout[(size_t)l*DINNER + d0 + c] = yv;
    }
    __syncthreads();
  }
}

// ---------------- gate: dot(8) + softmax + top2 + renorm + count ----------------
__global__ __launch_bounds__(256) void gate_topk_k(
    const float* __restrict__ xn, const float* __restrict__ gw,
    int* __restrict__ tidx, float* __restrict__ tw, int* __restrict__ cnt)
{
  const int l = blockIdx.x;
  const int t = threadIdx.x;
  const float4 xv = *(const float4*)&xn[(size_t)l*DIM_ + t*4];
  float acc[NEXP];
  #pragma unroll
  for (int e=0;e<NEXP;e++){
    const float4 g = *(const float4*)&gw[(size_t)e*DIM_ + t*4];
    acc[e] = xv.x*g.x + xv.y*g.y + xv.z*g.z + xv.w*g.w;
  }
  #pragma unroll
  for (int e=0;e<NEXP;e++)
    #pragma unroll
    for (int off=1; off<64; off<<=1) acc[e] += __shfl_xor(acc[e], off);
  __shared__ float red[4][NEXP];
  if ((t & 63)==0){
    #pragma unroll
    for (int e=0;e<NEXP;e++) red[t>>6][e] = acc[e];
  }
  __syncthreads();
  if (t==0){
    float g[NEXP];
    float m = -1e30f;
    #pragma unroll
    for (int e=0;e<NEXP;e++){ g[e]=red[0][e]+red[1][e]+red[2][e]+red[3][e]; m=fmaxf(m,g[e]); }
    float p[NEXP];
    #pragma unroll
    for (int e=0;e<NEXP;e++) p[e] = expf(g[e]-m);
    int i0=0;
    #pragma unroll
    for (int e=1;e<NEXP;e++) if (p[e] > p[i0]) i0=e;
    int i1 = (i0==0)?1:0;
    #pragma unroll
    for (int e=0;e<NEXP;e++) if (e!=i0 && p[e] > p[i1]) i1=e;
    const float w0=p[i0], w1=p[i1], inv=1.f/(w0+w1);
    tidx[2*l]=i0; tidx[2*l+1]=i1;
    tw[2*l]=w0*inv; tw[2*l+1]=w1*inv;
    atomicAdd(&cnt[i0],1); atomicAdd(&cnt[i1],1);
  }
}

// padded offsets: each expert region rounded up to 128 rows
__global__ void offsets_k(const int* __restrict__ cnt, int* __restrict__ poffs){
  if (threadIdx.x==0){
    int a=0;
    for (int e=0;e<NEXP;e++){ poffs[e]=a; a += ((cnt[e]+127)>>7)<<7; }
    poffs[NEXP]=a;
  }
}

__global__ __launch_bounds__(256) void scatter_k(
    const int* __restrict__ tidx, const int* __restrict__ poffs,
    int* __restrict__ cur, int* __restrict__ slot)
{
  const int t = blockIdx.x*256 + threadIdx.x;
  if (t >= L_SEQ) return;
  #pragma unroll
  for (int k=0;k<2;k++){
    const int e = tidx[2*t+k];
    slot[2*t+k] = poffs[e] + atomicAdd(&cur[e],1);
  }
}

// gather token rows into padded bf16 A for the expert GEMM
__global__ __launch_bounds__(256) void gather_bf16_k(
    const float* __restrict__ xm2n, const int* __restrict__ slot,
    ushort_t* __restrict__ Ag)
{
  const int t = blockIdx.x;
  const int c = threadIdx.x*4;
  const float4 v = *(const float4*)&xm2n[(size_t)t*DIM_ + c];
  ushort4 o; o.x=f2bf(v.x); o.y=f2bf(v.y); o.z=f2bf(v.z); o.w=f2bf(v.w);
  const int s0 = slot[2*t], s1 = slot[2*t+1];
  *(ushort4*)&Ag[(size_t)s0*DIM_ + c] = o;
  *(ushort4*)&Ag[(size_t)s1*DIM_ + c] = o;
}

// ---------------- final: out = skip + w0*y2[slot0] + w1*y2[slot1] ----------------
__global__ __launch_bounds__(256) void final_k(
    const float* __restrict__ x, const float* __restrict__ y2,
    const int* __restrict__ slot, const float* __restrict__ tw,
    float* __restrict__ out)
{
  const int l = blockIdx.x;
  const int c = threadIdx.x*4;
  const float4 xv = *(const float4*)&x[(size_t)l*DIM_ + c];
  const int s0 = slot[2*l], s1 = slot[2*l+1];
  const float w0 = tw[2*l], w1 = tw[2*l+1];
  const float4 a = *(const float4*)&y2[(size_t)s0*DIM_ + c];
  const float4 b = *(const float4*)&y2[(size_t)s1*DIM_ + c];
  float4 r;
  r.x = xv.x + w0*a.x + w1*b.x;
  r.y = xv.y + w0*a.y + w1*b.y;
  r.z = xv.z + w0*a.z + w1*b.z;
  r.w = xv.w + w0*a.w + w1*b.w;
  *(float4*)&out[(size_t)l*DIM_ + c] = r;
}

extern "C" void kernel_launch(void* const* d_in, const int* in_sizes, int n_in,
                              void* d_out, int out_size, void* d_ws, size_t ws_size,
                              hipStream_t stream) {
  const float* x         = (const float*)d_in[0];
  const float* in_proj_w = (const float*)d_in[1];
  const float* conv_w    = (const float*)d_in[2];
  const float* conv_b    = (const float*)d_in[3];
  const float* x_proj_w  = (const float*)d_in[4];
  const float* dt_proj_w = (const float*)d_in[5];
  const float* dt_proj_b = (const float*)d_in[6];
  const float* A_log     = (const float*)d_in[7];
  const float* Dp        = (const float*)d_in[8];
  const float* out_proj_w= (const float*)d_in[9];
  const float* gate_w    = (const float*)d_in[10];
  const float* w1        = (const float*)d_in[11];
  const float* w2        = (const float*)d_in[12];
  float* out = (float*)d_out;

  float* f = (float*)d_ws;
  float* xn    = f;  f += (size_t)2097152;   // (L,DIM)            [live: rms1..out_proj]
  float* xr    = f;  f += (size_t)8388608;   // (L,2*DINNER)       ┐ hbuf alias later
  float* xc    = f;  f += (size_t)4194304;   // (L,DINNER)         ┘
  float* xdbl  = f;  f += (size_t)262144;    // (L,96)             ┐
  float* delta = f;  f += (size_t)4194304;   // (L,DINNER)         ├ y2 + Ag alias later
  float* yg    = f;  f += (size_t)4194304;   // (L,DINNER)         ┘
  float* xm2   = f;  f += (size_t)2097152;   // (L,DIM)
  ushort_t* w1_bf = (ushort_t*)f; f += (size_t)16777216;  // 8*4096*1024 bf16
  ushort_t* w2_bf = (ushort_t*)f; f += (size_t)16777216;  // 8*1024*4096 bf16
  float* tw    = f;  f += 2*L_SEQ;
  int* tidx = (int*)f;
  int* cnt  = tidx + 2*L_SEQ;
  int* cur  = cnt + 16;
  int* poffs= cur + 16;
  int* slot = poffs + 16;
  // Aliases (temporally disjoint):
  float*    xm2n = xn;                                   // xn dead after out_proj epilogue
  ushort_t* hbuf = (ushort_t*)xr;                        // PADM*HIDDEN bf16 (10.5M fl of 12M region)
  float*    y2   = xdbl;                                 // PADM*DIM fp32 (5.24M of 8.65M region)
  ushort_t* Ag   = (ushort_t*)(xdbl + 5242880);          // PADM*DIM bf16 (2.62M fl, after y2)

  // 0. weight conversion (const inputs; ws is re-poisoned every call so must redo)
  cvt_bf16_k<<<2048, 256, 0, stream>>>(w1, w1_bf, (NEXP*HIDDEN*DIM_)/4);
  cvt_bf16_k<<<2048, 256, 0, stream>>>(w2, w2_bf, (NEXP*DIM_*HIDDEN)/4);
  // 1. xn = rmsnorm(x)
  rmsnorm_k<<<L_SEQ, 256, 0, stream>>>(x, xn);
  // 2. xr = xn @ in_proj_w^T  (fp32 — upstream of gate decisions)
  gemm_nt<0><<<dim3(L_SEQ/TM, 2*DINNER/TN), 256, 0, stream>>>(
      xn, DIM_, in_proj_w, DIM_, xr, 2*DINNER, L_SEQ, 2*DINNER, DIM_, nullptr, nullptr, 0);
  // 3. xc = silu(causal conv(xm) + b)
  conv_silu_k<<<dim3(L_SEQ, DINNER/256), 256, 0, stream>>>(xr, conv_w, conv_b, xc);
  // 4. xdbl = xc @ x_proj_w^T
  gemm_nt<0><<<dim3(L_SEQ/TM, (96+TN-1)/TN), 256, 0, stream>>>(
      xc, DINNER, x_proj_w, DINNER, xdbl, 96, L_SEQ, 96, DINNER, nullptr, nullptr, 0);
  // 5. delta = softplus(dt @ dt_proj_w^T + b)
  gemm_nt<1><<<dim3(L_SEQ/TM, DINNER/TN), 256, 0, stream>>>(
      xdbl, 96, dt_proj_w, DTRANK, delta, DINNER, L_SEQ, DINNER, DTRANK, dt_proj_b, nullptr, 0);
  // 6. selective scan (fused (+u*D)*silu(res))
  scan_k<<<DINNER/16, 256, 0, stream>>>(delta, xc, xdbl, xr + DINNER, A_log, Dp, yg);
  // 7. xm2 = yg @ out_proj_w^T + xn
  gemm_nt<3><<<dim3(L_SEQ/TM, DIM_/TN), 256, 0, stream>>>(
      yg, DINNER, out_proj_w, DINNER, xm2, DIM_, L_SEQ, DIM_, DINNER, nullptr, xn, DIM_);
  // 8. xm2n = rmsnorm(xm2)
  rmsnorm_k<<<L_SEQ, 256, 0, stream>>>(xm2, xm2n);
  // 9. routing (fp32 gate == baseline → identical expert decisions)
  hipMemsetAsync(cnt, 0, 32*sizeof(int), stream);
  gate_topk_k<<<L_SEQ, 256, 0, stream>>>(xm2n, gate_w, tidx, tw, cnt);
  offsets_k<<<1, 64, 0, stream>>>(cnt, poffs);
  scatter_k<<<L_SEQ/256, 256, 0, stream>>>(tidx, poffs, cur, slot);
  gather_bf16_k<<<L_SEQ, 256, 0, stream>>>(xm2n, slot, Ag);
  // 10. MoE expert GEMMs — bf16 MFMA, padded tiles (pad rows compute garbage, never read)
  gemm_bf16<2, true><<<dim3(PADM/128, HIDDEN/128), 256, 0, stream>>>(
      Ag, w1_bf, (size_t)HIDDEN*DIM_, hbuf, HIDDEN, DIM_, poffs);
  gemm_bf16<0, true><<<dim3(PADM/128, DIM_/128), 256, 0, stream>>>(
      hbuf, w2_bf, (size_t)DIM_*HIDDEN, y2, DIM_, HIDDEN, poffs);
  // 11. combine
  final_k<<<L_SEQ, 256, 0, stream>>>(x, y2, slot, tw, out);
}